// Round 8
// baseline (375.075 us; speedup 1.0000x reference)
//
#include <hip/hip_runtime.h>
#include <hip/hip_bf16.h>

#define NN 100000
#define DD 64
#define EE 400000
#define TT 5

#define CH 40                    /* coarse src buckets (chunks) */
#define BPC 2500                 /* NN/CH exact */
#define PSPLIT 32                /* partition slices per t */
#define PESL (EE / PSPLIT)       /* 12,500 edges per slice */
#define PBN (TT * CH * PSPLIT)   /* 6400 partition counters */
#define PB_IDX(t, c, s) ((((t) * CH + (c)) * PSPLIT) + (s))

#define SCAN_TOTAL 500000        /* T*N bins */
#define SCAN_T 256
#define SCAN_PER 1024            /* bins per scan block */
#define SCAN_B 512               /* 512*1024 >= 500000 */

#define WPT 12500                /* 32-edge windows per t (EE/32) */
#define NWIN (TT * WPT)          /* 62,500 windows total */
#define EGRID 2048               /* k_edge6 blocks (8192 persistent waves) */

typedef __bf16 bf16x8 __attribute__((ext_vector_type(8)));
typedef float  f32x4  __attribute__((ext_vector_type(4)));

// ws layout (bytes) — total 40,914,240 (unchanged envelope)
#define OFF_XBF  0u            // N*D ushort      = 12,800,000
#define OFF_WT   12800000u     // T*64*128 ushort = 81,920
#define OFF_CTOT 12881920u     // T*N u32 (cnt_tot) = 2,000,000
#define OFF_WGT  14881920u     // T f32 (pad 64)
#define OFF_CUR  14881984u     // T*N u32 (scan of totals) = 2,000,000
#define OFF_BS   16881984u     // 512 u32 (pad 2048)
#define OFF_BO   16884032u     // 512 u32 (pad 2048)
#define OFF_PE   16886080u     // 2M u32 packed (src_local<<17|dst) = 8,000,000
#define OFF_PB   24886080u     // 6401 u32 partition scan (25,604 B < 28,160 slack)
#define OFF_DST  24914240u     // 2M int (sorted dst) = 8,000,000
#define OFF_SEG  32914240u     // 2M int (seg src)    = 8,000,000 -> 40,914,240

__device__ __forceinline__ unsigned short f2bf(float f) {
    union { float f; unsigned u; } v; v.f = f;
    unsigned u = v.u;
    return (unsigned short)((u + 0x7FFFu + ((u >> 16) & 1u)) >> 16);  // RNE
}

// ---------------- Phase 1: init / convert / out-zero, FUSED pcount -----------
__global__ __launch_bounds__(256) void k_init(
        const float* __restrict__ x, const float* __restrict__ W,
        const float* __restrict__ ea, const int* __restrict__ edges,
        unsigned short* __restrict__ xbf, unsigned short* __restrict__ wT,
        float* __restrict__ wgt, float* __restrict__ out,
        unsigned* __restrict__ pcnt) {
    int i = blockIdx.x * blockDim.x + threadIdx.x;   // grid covers N*D exactly
    if (i < NN * DD) {
        out[i] = 0.0f;
        xbf[i] = f2bf(x[i]);
    }
    if (i < TT * 128 * 64) {
        int t = i >> 13;          // /8192
        int rem = i & 8191;
        int d = rem >> 7;         // /128
        int k = rem & 127;
        wT[i] = f2bf(W[t * 8192 + k * 64 + d]);   // wT[t][d][k] = W[t][k][d]
    }
    if (i == 0) {
        float m = -1e30f;
        for (int t = 0; t < TT; t++) m = fmaxf(m, ea[t]);
        float e[TT]; float s = 0.0f;
        for (int t = 0; t < TT; t++) { e[t] = __expf(ea[t] - m); s += e[t]; }
        for (int t = 0; t < TT; t++) wgt[t] = e[t] / s;
    }
    // fused pcount: 160 (slice, t) pairs on blocks 0..159 (block-uniform branch)
    if (blockIdx.x < PSPLIT * TT) {
        const int s = blockIdx.x & (PSPLIT - 1);
        const int t = blockIdx.x >> 5;               // PSPLIT == 32
        __shared__ unsigned h[CH];
        if (threadIdx.x < CH) h[threadIdx.x] = 0u;
        __syncthreads();
        const int4* srcp = reinterpret_cast<const int4*>(edges + (size_t)t * 2 * EE + s * PESL);
        for (int j = threadIdx.x; j < PESL / 4; j += 256) {
            int4 v = srcp[j];
            atomicAdd(&h[(unsigned)v.x / BPC], 1u);
            atomicAdd(&h[(unsigned)v.y / BPC], 1u);
            atomicAdd(&h[(unsigned)v.z / BPC], 1u);
            atomicAdd(&h[(unsigned)v.w / BPC], 1u);
        }
        __syncthreads();
        if (threadIdx.x < CH) pcnt[PB_IDX(t, threadIdx.x, s)] = h[threadIdx.x];
    }
}

// ---------------- Phase 2b: exclusive scan of 6400 partition counters --------
__global__ void k_pscan(unsigned* __restrict__ pb) {
    __shared__ unsigned s[512];
    const int tid = threadIdx.x;
    unsigned v[13]; unsigned sum = 0u;
#pragma unroll
    for (int j = 0; j < 13; j++) {
        int g = tid * 13 + j;
        v[j] = (g < PBN) ? pb[g] : 0u;
        sum += v[j];
    }
    s[tid] = sum;
    __syncthreads();
    unsigned inc = sum;
    for (int d = 1; d < 512; d <<= 1) {
        unsigned a = (tid >= d) ? s[tid - d] : 0u;
        __syncthreads();
        inc += a;
        s[tid] = inc;
        __syncthreads();
    }
    unsigned run = inc - sum;
#pragma unroll
    for (int j = 0; j < 13; j++) {
        int g = tid * 13 + j;
        if (g < PBN) pb[g] = run;
        run += v[j];
    }
    if (tid == 511) pb[PBN] = run;   // sentinel = 2,000,000
}

// ---------------- Phase 2c: partition scatter, (src_local:12 | dst:17) -------
__global__ __launch_bounds__(256) void k_pscat(const int* __restrict__ edges,
                                               const unsigned* __restrict__ pbase,
                                               unsigned* __restrict__ pe) {
    const int s = blockIdx.x, t = blockIdx.y;
    __shared__ unsigned lofs[CH];
    if (threadIdx.x < CH) lofs[threadIdx.x] = pbase[PB_IDX(t, threadIdx.x, s)];
    __syncthreads();
    const int* srcp = edges + (size_t)t * 2 * EE + s * PESL;
    const int* dstp = srcp + EE;
    for (int i = threadIdx.x; i < PESL / 4; i += 256) {
        int4 v = reinterpret_cast<const int4*>(srcp)[i];
        int4 w = reinterpret_cast<const int4*>(dstp)[i];
        {
            unsigned c = (unsigned)v.x / BPC;
            unsigned o = atomicAdd(&lofs[c], 1u);
            pe[o] = (((unsigned)v.x - c * BPC) << 17) | (unsigned)w.x;
        }
        {
            unsigned c = (unsigned)v.y / BPC;
            unsigned o = atomicAdd(&lofs[c], 1u);
            pe[o] = (((unsigned)v.y - c * BPC) << 17) | (unsigned)w.y;
        }
        {
            unsigned c = (unsigned)v.z / BPC;
            unsigned o = atomicAdd(&lofs[c], 1u);
            pe[o] = (((unsigned)v.z - c * BPC) << 17) | (unsigned)w.z;
        }
        {
            unsigned c = (unsigned)v.w / BPC;
            unsigned o = atomicAdd(&lofs[c], 1u);
            pe[o] = (((unsigned)v.w - c * BPC) << 17) | (unsigned)w.w;
        }
    }
}

// ---------------- Phase 2d: exact per-src counts from bucketed pe ------------
__global__ __launch_bounds__(512) void k_bcount(const unsigned* __restrict__ pe,
                                                const unsigned* __restrict__ pbase,
                                                unsigned* __restrict__ cnt_tot) {
    const int c = blockIdx.x, t = blockIdx.y;
    __shared__ unsigned h[BPC];
    for (int i = threadIdx.x; i < BPC; i += 512) h[i] = 0u;
    __syncthreads();
    const unsigned st = pbase[PB_IDX(t, c, 0)];
    const unsigned en = pbase[((t * CH + c) + 1) * PSPLIT];
    for (unsigned i = st + threadIdx.x; i < en; i += 512)
        atomicAdd(&h[pe[i] >> 17], 1u);
    __syncthreads();
    unsigned* outp = cnt_tot + t * NN + c * BPC;
    for (int i = threadIdx.x; i < BPC; i += 512) outp[i] = h[i];
}

// ---------------- Phase 2e: global exclusive scan over T*N bins --------------
__global__ void k_scan1(const unsigned* __restrict__ cnt_tot,
                        unsigned* __restrict__ cur, unsigned* __restrict__ bsum) {
    __shared__ unsigned s[SCAN_T];
    const int b = blockIdx.x, tid = threadIdx.x;
    const int base = b * SCAN_PER + tid * 4;
    unsigned tot[4] = {0u, 0u, 0u, 0u};
    if (base < SCAN_TOTAL) {
        uint4 tv = *reinterpret_cast<const uint4*>(cnt_tot + base);
        tot[0] = tv.x; tot[1] = tv.y; tot[2] = tv.z; tot[3] = tv.w;
    }
    const unsigned tsum = tot[0] + tot[1] + tot[2] + tot[3];
    s[tid] = tsum;
    __syncthreads();
    unsigned inc = tsum;
    for (int d = 1; d < SCAN_T; d <<= 1) {
        unsigned add = (tid >= d) ? s[tid - d] : 0u;
        __syncthreads();
        inc += add;
        s[tid] = inc;
        __syncthreads();
    }
    if (tid == SCAN_T - 1) bsum[b] = inc;
    const unsigned p0 = inc - tsum;
    if (base < SCAN_TOTAL) {
        *reinterpret_cast<uint4*>(cur + base) =
            make_uint4(p0, p0 + tot[0], p0 + tot[0] + tot[1], p0 + tot[0] + tot[1] + tot[2]);
    }
}

__global__ void k_scan2(const unsigned* __restrict__ bsum, unsigned* __restrict__ boff) {
    __shared__ unsigned s[SCAN_B];
    const int tid = threadIdx.x;
    const unsigned v = bsum[tid];
    s[tid] = v;
    __syncthreads();
    unsigned inc = v;
    for (int d = 1; d < SCAN_B; d <<= 1) {
        unsigned add = (tid >= d) ? s[tid - d] : 0u;
        __syncthreads();
        inc += add;
        s[tid] = inc;
        __syncthreads();
    }
    boff[tid] = inc - v;
}

// ---------------- Phase 2f: counting-sort fill + fused seg write -------------
__global__ __launch_bounds__(512) void k_bfill(const unsigned* __restrict__ pe,
                                               const unsigned* __restrict__ pbase,
                                               const unsigned* __restrict__ cur,
                                               const unsigned* __restrict__ boff,
                                               const unsigned* __restrict__ cnt_tot,
                                               int* __restrict__ sdst,
                                               int* __restrict__ seg) {
    const int c = blockIdx.x, t = blockIdx.y;
    __shared__ unsigned curl[BPC];
    const int n0 = c * BPC;
    for (int i = threadIdx.x; i < BPC; i += 512) {
        int g = t * NN + n0 + i;
        unsigned start = cur[g] + boff[g >> 10];
        curl[i] = start;
        unsigned cc = cnt_tot[g];
        int node = n0 + i;
        for (unsigned j = 0; j < cc; j++) seg[start + j] = node;
    }
    __syncthreads();
    const unsigned st = pbase[PB_IDX(t, c, 0)];
    const unsigned en = pbase[((t * CH + c) + 1) * PSPLIT];
    for (unsigned i = st + threadIdx.x; i < en; i += 512) {
        unsigned p = pe[i];
        sdst[atomicAdd(&curl[p >> 17], 1u)] = (int)(p & 0x1FFFFu);
    }
}

// ---------------- Phase 3 (v6): persistent wave-independent pipelined k_edge.
// Same windows / sort / flush / atomics as the proven R0 kernel — ONLY the
// latency structure changes. Facts exploited: every hot-path LDS structure is
// wave-private (Ab rows [32w,32w+32), src_s/scale_s slices, proj) -> R0's two
// barriers were inert; each wave becomes an independent persistent stream over
// 32-edge windows with a depth-2 pipeline: rows(i+1)+cnt(i+1) in flight during
// compute(i) (900cy HBM gather hidden under ~700cy MFMA+reduce), idx(i+2) in
// flight one stage earlier. Registers: rows buffer 8xfloat4 single-buffered
// (consumed by ds_write at stage, refilled by prefetch — WAR only, static
// names, rule #20 safe). Discriminating experiment: win -> k_edge was
// latency-exposure-bound; null -> atomic-service floor confirmed. ------------
__global__ __launch_bounds__(256, 4) void k_edge6(
    const unsigned short* __restrict__ xbf, const unsigned short* __restrict__ wT,
    const float* __restrict__ b, const int* __restrict__ sdst,
    const int* __restrict__ seg, const unsigned* __restrict__ cnt,
    const float* __restrict__ wgt, float* __restrict__ out) {

    __shared__ __align__(16) unsigned short Ab[128][136];   // feats; reused as f32 proj[128][68]
    __shared__ float scale_s[128];
    __shared__ int   src_s[132];                             // padded

    const int tid = threadIdx.x;
    const int wv = tid >> 6, lane = tid & 63;
    const int m16 = lane & 15, quad = lane >> 4;
    const int el = lane >> 1, half = lane & 1;               // gather role
    const int row = wv * 32 + el;                            // this thread's LDS row
    const int j0 = wv * 32;
    const int WSTRIDE = EGRID * 4;

    unsigned wcur = blockIdx.x * 4 + wv;                     // first window
    if (wcur >= NWIN) return;

    // ---- prologue: window wcur -> idx, cnt, rows all in flight ----
    unsigned tC = wcur / WPT;
    unsigned e0C = (wcur - tC * WPT) * 32u;
    {
        size_t pos = (size_t)tC * EE + e0C + el;
        int iC0 = half ? sdst[pos] : seg[pos];
        // (fallthrough into loop state below)
        // rows + cnt for first window:
        // declared here to keep live ranges tight
        (void)iC0;
    }
    // loop-carried state
    int iC;            // idx of the window about to be STAGED (rows in r0..r7)
    unsigned cC = 1u;  // cnt for scale (half==0 lanes)
    float4 r0, r1, r2, r3, r4, r5, r6, r7;                   // staged rows
    {
        size_t pos = (size_t)tC * EE + e0C + el;
        iC = half ? sdst[pos] : seg[pos];
        if (half == 0) cC = cnt[tC * NN + iC];
        const float4* g = reinterpret_cast<const float4*>(xbf + (size_t)iC * 64);
        r0 = g[0]; r1 = g[1]; r2 = g[2]; r3 = g[3];
        r4 = g[4]; r5 = g[5]; r6 = g[6]; r7 = g[7];
    }
    // idx for window wcur+WSTRIDE (depth-2)
    unsigned wnxt = wcur + WSTRIDE;
    unsigned tN = 0, e0N = 0;
    int iN = 0;
    if (wnxt < NWIN) {
        tN = wnxt / WPT; e0N = (wnxt - tN * WPT) * 32u;
        size_t pos = (size_t)tN * EE + e0N + el;
        iN = half ? sdst[pos] : seg[pos];
    }

    while (true) {
        // ---- stage current window into LDS (waits rows via value dep) ----
        {
            float4* l = reinterpret_cast<float4*>(&Ab[row][half * 64]);
            l[0] = r0; l[1] = r1; l[2] = r2; l[3] = r3;
            l[4] = r4; l[5] = r5; l[6] = r6; l[7] = r7;
            if (half == 0) {
                src_s[row] = iC;
                scale_s[row] = __ldg(wgt + tC) / (float)cC;
            }
        }
        const unsigned tcomp = tC;                    // compute uses pre-rotation t

        // ---- rotate + prefetch (rows/cnt for next, idx for next-next) ----
        const bool more = (wnxt < NWIN);
        const unsigned wn2 = wnxt + WSTRIDE;
        if (more) {
            tC = tN; e0C = e0N; iC = iN;
            if (half == 0) cC = cnt[tC * NN + iC];
            const float4* g = reinterpret_cast<const float4*>(xbf + (size_t)iC * 64);
            r0 = g[0]; r1 = g[1]; r2 = g[2]; r3 = g[3];
            r4 = g[4]; r5 = g[5]; r6 = g[6]; r7 = g[7];
            if (wn2 < NWIN) {
                tN = wn2 / WPT; e0N = (wn2 - tN * WPT) * 32u;
                size_t pos = (size_t)tN * EE + e0N + el;
                iN = half ? sdst[pos] : seg[pos];
            }
        }

        // ---- compute current window (R0 body, t = tcomp) ----
        {
            const unsigned short* wrow = wT + (size_t)tcomp * 8192;   // [d][k]

            f32x4 acc[2][4];
#pragma unroll
            for (int tm = 0; tm < 2; tm++)
#pragma unroll
                for (int tn = 0; tn < 4; tn++)
                    acc[tm][tn] = (f32x4){0.f, 0.f, 0.f, 0.f};

#pragma unroll
            for (int kk = 0; kk < 128; kk += 32) {
                const int kb = kk + quad * 8;
                bf16x8 af[2], bfr[4];
#pragma unroll
                for (int tm = 0; tm < 2; tm++)
                    af[tm] = *reinterpret_cast<const bf16x8*>(&Ab[j0 + tm * 16 + m16][kb]);
#pragma unroll
                for (int tn = 0; tn < 4; tn++)
                    bfr[tn] = *reinterpret_cast<const bf16x8*>(wrow + (tn * 16 + m16) * 128 + kb);
#pragma unroll
                for (int tm = 0; tm < 2; tm++)
#pragma unroll
                    for (int tn = 0; tn < 4; tn++)
                        acc[tm][tn] = __builtin_amdgcn_mfma_f32_16x16x32_bf16(
                            af[tm], bfr[tn], acc[tm][tn], 0, 0, 0);
            }

            float bias[4];
#pragma unroll
            for (int tn = 0; tn < 4; tn++) bias[tn] = b[tcomp * 64 + tn * 16 + m16];

            float* proj = reinterpret_cast<float*>(&Ab[0][0]);   // [128][68] f32
#pragma unroll
            for (int tm = 0; tm < 2; tm++) {
#pragma unroll
                for (int r = 0; r < 4; r++) {
                    const int eloc = j0 + tm * 16 + quad * 4 + r;
                    const float s = scale_s[eloc];
#pragma unroll
                    for (int tn = 0; tn < 4; tn++) {
                        float v = acc[tm][tn][r] + bias[tn];
                        v = v > 0.f ? v : 0.f;
                        proj[eloc * 68 + tn * 16 + m16] = v * s;
                    }
                }
            }

            // wave-cooperative segmented reduce; coalesced 256B atomic bursts
            float sum = 0.f;
#pragma unroll
            for (int j = j0; j < j0 + 32; j++) {
                sum += proj[j * 68 + lane];
                const bool flush = (j == j0 + 31) || (src_s[j + 1] != src_s[j]);
                if (flush) {
                    atomicAdd(out + (size_t)src_s[j] * 64 + lane, sum);
                    sum = 0.f;
                }
            }
        }

        if (!more) break;
        wnxt = wn2;
    }
}

extern "C" void kernel_launch(void* const* d_in, const int* in_sizes, int n_in,
                              void* d_out, int out_size, void* d_ws, size_t ws_size,
                              hipStream_t stream) {
    const float* x     = (const float*)d_in[0];
    const float* W     = (const float*)d_in[1];
    const float* b     = (const float*)d_in[2];
    const float* ea    = (const float*)d_in[3];
    const int*   edges = (const int*)d_in[4];
    float* out = (float*)d_out;

    char* ws = (char*)d_ws;
    unsigned short* xbf  = (unsigned short*)(ws + OFF_XBF);
    unsigned short* wT   = (unsigned short*)(ws + OFF_WT);
    unsigned* cnt_tot    = (unsigned*)(ws + OFF_CTOT);
    float* wgt           = (float*)(ws + OFF_WGT);
    unsigned* cur        = (unsigned*)(ws + OFF_CUR);
    unsigned* bsum       = (unsigned*)(ws + OFF_BS);
    unsigned* boff       = (unsigned*)(ws + OFF_BO);
    unsigned* pe         = (unsigned*)(ws + OFF_PE);
    unsigned* pb         = (unsigned*)(ws + OFF_PB);
    int* sdst            = (int*)(ws + OFF_DST);
    int* seg             = (int*)(ws + OFF_SEG);

    // Phase 1: out-zero, x->bf16, W^T, softmax + FUSED partition counts
    k_init<<<(NN * DD) / 256, 256, 0, stream>>>(x, W, ea, edges, xbf, wT, wgt, out, pb);

    // Phase 2: single-read partition sort (widened CH=40, proven ~135 us)
    k_pscan<<<1, 512, 0, stream>>>(pb);
    k_pscat<<<dim3(PSPLIT, TT), 256, 0, stream>>>(edges, pb, pe);
    k_bcount<<<dim3(CH, TT), 512, 0, stream>>>(pe, pb, cnt_tot);
    k_scan1<<<SCAN_B, SCAN_T, 0, stream>>>(cnt_tot, cur, bsum);
    k_scan2<<<1, SCAN_B, 0, stream>>>(bsum, boff);
    k_bfill<<<dim3(CH, TT), 512, 0, stream>>>(pe, pb, cur, boff, cnt_tot, sdst, seg);

    // Phase 3: persistent pipelined MFMA gather-GEMM + segmented atomic scatter
    k_edge6<<<EGRID, 256, 0, stream>>>(xbf, wT, b, sdst, seg, cnt_tot, wgt, out);
}

// Round 9
// 317.365 us; speedup vs baseline: 1.1818x; 1.1818x over previous
//
#include <hip/hip_runtime.h>
#include <hip/hip_bf16.h>

#define NN 100000
#define DD 64
#define EE 400000
#define TT 5

#define CH 40                    /* coarse src buckets (chunks) */
#define BPC 2500                 /* NN/CH exact */
#define PSPLIT 32                /* partition slices per t */
#define PESL (EE / PSPLIT)       /* 12,500 edges per slice */
#define PBN (TT * CH * PSPLIT)   /* 6400 partition counters = 256*25 exact */
#define PB_IDX(t, c, s) ((((t) * CH + (c)) * PSPLIT) + (s))

typedef __bf16 bf16x8 __attribute__((ext_vector_type(8)));
typedef float  f32x4  __attribute__((ext_vector_type(4)));

// ws layout (bytes) — total 40,914,240 envelope (cur/bs/bo regions now unused)
#define OFF_XBF  0u            // N*D ushort      = 12,800,000
#define OFF_WT   12800000u     // T*64*128 ushort = 81,920
#define OFF_CTOT 12881920u     // T*N u32 (cnt_tot) = 2,000,000
#define OFF_WGT  14881920u     // T f32 (pad 64)
#define OFF_PE   16886080u     // 2M u32 packed (src_local<<17|dst) = 8,000,000
#define OFF_PB   24886080u     // 6400 u32 RAW partition counts (25,600 B)
#define OFF_DST  24914240u     // 2M int (sorted dst) = 8,000,000
#define OFF_SEG  32914240u     // 2M int (seg src)    = 8,000,000 -> 40,914,240

__device__ __forceinline__ unsigned short f2bf(float f) {
    union { float f; unsigned u; } v; v.f = f;
    unsigned u = v.u;
    return (unsigned short)((u + 0x7FFFu + ((u >> 16) & 1u)) >> 16);  // RNE
}

// ---------------- Phase 1: init / convert / out-zero, FUSED pcount -----------
__global__ __launch_bounds__(256) void k_init(
        const float* __restrict__ x, const float* __restrict__ W,
        const float* __restrict__ ea, const int* __restrict__ edges,
        unsigned short* __restrict__ xbf, unsigned short* __restrict__ wT,
        float* __restrict__ wgt, float* __restrict__ out,
        unsigned* __restrict__ pcnt) {
    int i = blockIdx.x * blockDim.x + threadIdx.x;   // grid covers N*D exactly
    if (i < NN * DD) {
        out[i] = 0.0f;
        xbf[i] = f2bf(x[i]);
    }
    if (i < TT * 128 * 64) {
        int t = i >> 13;          // /8192
        int rem = i & 8191;
        int d = rem >> 7;         // /128
        int k = rem & 127;
        wT[i] = f2bf(W[t * 8192 + k * 64 + d]);   // wT[t][d][k] = W[t][k][d]
    }
    if (i == 0) {
        float m = -1e30f;
        for (int t = 0; t < TT; t++) m = fmaxf(m, ea[t]);
        float e[TT]; float s = 0.0f;
        for (int t = 0; t < TT; t++) { e[t] = __expf(ea[t] - m); s += e[t]; }
        for (int t = 0; t < TT; t++) wgt[t] = e[t] / s;
    }
    // fused pcount: 160 (slice, t) pairs on blocks 0..159 (block-uniform branch)
    if (blockIdx.x < PSPLIT * TT) {
        const int s = blockIdx.x & (PSPLIT - 1);
        const int t = blockIdx.x >> 5;               // PSPLIT == 32
        __shared__ unsigned h[CH];
        if (threadIdx.x < CH) h[threadIdx.x] = 0u;
        __syncthreads();
        const int4* srcp = reinterpret_cast<const int4*>(edges + (size_t)t * 2 * EE + s * PESL);
        for (int j = threadIdx.x; j < PESL / 4; j += 256) {
            int4 v = srcp[j];
            atomicAdd(&h[(unsigned)v.x / BPC], 1u);
            atomicAdd(&h[(unsigned)v.y / BPC], 1u);
            atomicAdd(&h[(unsigned)v.z / BPC], 1u);
            atomicAdd(&h[(unsigned)v.w / BPC], 1u);
        }
        __syncthreads();
        if (threadIdx.x < CH) pcnt[PB_IDX(t, threadIdx.x, s)] = h[threadIdx.x];
    }
}

// ---------------- Phase 2: partition scatter with REDUNDANT in-LDS scan of the
// raw pb counts (6400 u32, L2-hot). Kills the separate k_pscan launch: every
// block recomputes the full prefix itself (~2 us) and picks its 40 offsets. --
__global__ __launch_bounds__(256) void k_pscat(const int* __restrict__ edges,
                                               const unsigned* __restrict__ pb,
                                               unsigned* __restrict__ pe) {
    const int s = blockIdx.x, t = blockIdx.y;
    const int tid = threadIdx.x;
    __shared__ unsigned pbs[PBN];      // scanned copy (25.6 KB)
    __shared__ unsigned ssum[256];
    __shared__ unsigned lofs[CH];
    {
        const int base = tid * 25;     // PBN = 6400 = 256*25 exact
        unsigned v[25]; unsigned sum = 0u;
#pragma unroll
        for (int j = 0; j < 25; j++) { v[j] = pb[base + j]; sum += v[j]; }
        ssum[tid] = sum;
        __syncthreads();
        unsigned inc = sum;
        for (int d = 1; d < 256; d <<= 1) {
            unsigned a = (tid >= d) ? ssum[tid - d] : 0u;
            __syncthreads();
            inc += a;
            ssum[tid] = inc;
            __syncthreads();
        }
        unsigned run = inc - sum;      // exclusive prefix of this chunk
#pragma unroll
        for (int j = 0; j < 25; j++) { pbs[base + j] = run; run += v[j]; }
        __syncthreads();
        if (tid < CH) lofs[tid] = pbs[PB_IDX(t, tid, s)];
        __syncthreads();
    }
    const int* srcp = edges + (size_t)t * 2 * EE + s * PESL;
    const int* dstp = srcp + EE;
    for (int i = tid; i < PESL / 4; i += 256) {
        int4 v = reinterpret_cast<const int4*>(srcp)[i];
        int4 w = reinterpret_cast<const int4*>(dstp)[i];
        {
            unsigned c = (unsigned)v.x / BPC;
            unsigned o = atomicAdd(&lofs[c], 1u);
            pe[o] = (((unsigned)v.x - c * BPC) << 17) | (unsigned)w.x;
        }
        {
            unsigned c = (unsigned)v.y / BPC;
            unsigned o = atomicAdd(&lofs[c], 1u);
            pe[o] = (((unsigned)v.y - c * BPC) << 17) | (unsigned)w.y;
        }
        {
            unsigned c = (unsigned)v.z / BPC;
            unsigned o = atomicAdd(&lofs[c], 1u);
            pe[o] = (((unsigned)v.z - c * BPC) << 17) | (unsigned)w.z;
        }
        {
            unsigned c = (unsigned)v.w / BPC;
            unsigned o = atomicAdd(&lofs[c], 1u);
            pe[o] = (((unsigned)v.w - c * BPC) << 17) | (unsigned)w.w;
        }
    }
}

// ---------------- Phase 3: FUSED bucket sort — bcount + in-LDS bin scan +
// seg runs + scatter in ONE kernel. Replaces k_bcount + k_scan1 + k_scan2 +
// k_bfill (3 launches + 8 MB of cur/boff/cnt re-reads eliminated). Bucket
// start recomputed by block reduce over raw pb prefix (L2-hot, ~12 reads/thr).
// Absolute positions: bucket(t,c) start == prefix(pb)[PB_IDX(t,c,0)]; each t's
// segment starts at exactly t*EE (counts per t sum to EE), which k_edge's
// pos = t*EE + e0 + e indexing requires. ---------------------------------------
__global__ __launch_bounds__(512) void k_bsort(const unsigned* __restrict__ pe,
                                               const unsigned* __restrict__ pb,
                                               unsigned* __restrict__ cnt_tot,
                                               int* __restrict__ sdst,
                                               int* __restrict__ seg) {
    const int c = blockIdx.x, t = blockIdx.y;
    const int tid = threadIdx.x;
    __shared__ unsigned h[BPC];        // per-bin counts (10 KB)
    __shared__ unsigned curl[BPC];     // absolute positions (10 KB)
    __shared__ unsigned ssum[512];
    __shared__ unsigned stsh[2];

    const int K = (t * CH + c) * PSPLIT;   // raw-pb index of this bucket's slice 0

    // bucket start = sum pb[0..K)
    unsigned part = 0u;
    for (int i = tid; i < K; i += 512) part += pb[i];
    ssum[tid] = part;
    __syncthreads();
    for (int d = 256; d > 0; d >>= 1) {
        if (tid < d) ssum[tid] += ssum[tid + d];
        __syncthreads();
    }
    if (tid == 0) stsh[0] = ssum[0];
    // bucket size = sum pb[K..K+PSPLIT)
    unsigned part2 = (tid < PSPLIT) ? pb[K + tid] : 0u;
    __syncthreads();
    ssum[tid] = part2;
    __syncthreads();
    for (int d = 256; d > 0; d >>= 1) {
        if (tid < d) ssum[tid] += ssum[tid + d];
        __syncthreads();
    }
    if (tid == 0) stsh[1] = ssum[0];
    for (int i = tid; i < BPC; i += 512) h[i] = 0u;
    __syncthreads();
    const unsigned st = stsh[0];
    const unsigned en = st + stsh[1];

    // count bins
    for (unsigned i = st + tid; i < en; i += 512)
        atomicAdd(&h[pe[i] >> 17], 1u);
    __syncthreads();

    // cnt_tot for k_edge's scale
    unsigned* outp = cnt_tot + t * NN + c * BPC;
    for (int i = tid; i < BPC; i += 512) outp[i] = h[i];

    // block-wide exclusive scan of h -> absolute curl, fused seg runs
    {
        const int base = tid * 5;          // 512*5 = 2560 >= 2500
        unsigned v[5]; unsigned sum = 0u;
#pragma unroll
        for (int j = 0; j < 5; j++) {
            int g = base + j;
            v[j] = (g < BPC) ? h[g] : 0u;
            sum += v[j];
        }
        ssum[tid] = sum;
        __syncthreads();
        unsigned inc = sum;
        for (int d = 1; d < 512; d <<= 1) {
            unsigned a = (tid >= d) ? ssum[tid - d] : 0u;
            __syncthreads();
            inc += a;
            ssum[tid] = inc;
            __syncthreads();
        }
        unsigned run = st + inc - sum;     // absolute exclusive prefix
#pragma unroll
        for (int j = 0; j < 5; j++) {
            int g = base + j;
            if (g < BPC) {
                curl[g] = run;
                const int node = c * BPC + g;
                for (unsigned jj = 0; jj < v[j]; jj++) seg[run + jj] = node;
                run += v[j];
            }
        }
    }
    __syncthreads();

    // counting-sort scatter of dst
    for (unsigned i = st + tid; i < en; i += 512) {
        unsigned p = pe[i];
        sdst[atomicAdd(&curl[p >> 17], 1u)] = (int)(p & 0x1FFFFu);
    }
}

// ---------------- Phase 4: gather -> MFMA -> wave-cooperative segmented scatter.
// EXACT R0 kernel — 184.3 +/- 0.5 us across four reproductions. Variants tried
// and REVERTED: exclusive ownership (R1: 386, R5: 340), global-atomic fill
// (R3), 2x occupancy (R6: 282), persistent software pipeline (R8: 241 — HW
// block dispatch IS the pipeline; Common-mistake #5). DO NOT TOUCH. ----------
__global__ __launch_bounds__(256) void k_edge(
    const unsigned short* __restrict__ xbf, const unsigned short* __restrict__ wT,
    const float* __restrict__ b, const int* __restrict__ sdst,
    const int* __restrict__ seg, const unsigned* __restrict__ cnt,
    const float* __restrict__ wgt, float* __restrict__ out) {
    const int t  = blockIdx.y;
    const int e0 = blockIdx.x * 128;

    __shared__ __align__(16) unsigned short Ab[128][136];   // feats tile; reused as f32 proj[128][68]
    __shared__ float scale_s[128];
    __shared__ int   src_s[132];                             // padded

    const int tid = threadIdx.x;

    // stage A: gather x rows (bf16, 128B each); thread pair per sorted edge
    {
        int e = tid >> 1, half = tid & 1;
        size_t pos = (size_t)t * EE + e0 + e;
        int idx = half ? sdst[pos] : seg[pos];
        const float4* g = reinterpret_cast<const float4*>(xbf + (size_t)idx * 64);
        float4* l = reinterpret_cast<float4*>(&Ab[e][half * 64]);
#pragma unroll
        for (int c = 0; c < 8; c++) l[c] = g[c];
        if (half == 0) {
            src_s[e] = idx;
            scale_s[e] = wgt[t] / (float)cnt[t * NN + idx];   // cnt_tot table is L2-hot
        }
    }
    __syncthreads();

    const int wv = tid >> 6, lane = tid & 63;
    const int m16 = lane & 15, quad = lane >> 4;
    const unsigned short* wrow = wT + (size_t)t * 8192;      // [d][k], 64x128

    f32x4 acc[2][4];
#pragma unroll
    for (int tm = 0; tm < 2; tm++)
#pragma unroll
        for (int tn = 0; tn < 4; tn++)
            acc[tm][tn] = (f32x4){0.f, 0.f, 0.f, 0.f};

#pragma unroll
    for (int kk = 0; kk < 128; kk += 32) {
        const int kb = kk + quad * 8;
        bf16x8 af[2], bfr[4];
#pragma unroll
        for (int tm = 0; tm < 2; tm++)
            af[tm] = *reinterpret_cast<const bf16x8*>(&Ab[wv * 32 + tm * 16 + m16][kb]);
#pragma unroll
        for (int tn = 0; tn < 4; tn++)
            bfr[tn] = *reinterpret_cast<const bf16x8*>(wrow + (tn * 16 + m16) * 128 + kb);
#pragma unroll
        for (int tm = 0; tm < 2; tm++)
#pragma unroll
            for (int tn = 0; tn < 4; tn++)
                acc[tm][tn] = __builtin_amdgcn_mfma_f32_16x16x32_bf16(
                    af[tm], bfr[tn], acc[tm][tn], 0, 0, 0);
    }

    // all waves done reading Ab before we overwrite it with f32 proj
    __syncthreads();

    float bias[4];
#pragma unroll
    for (int tn = 0; tn < 4; tn++) bias[tn] = b[t * 64 + tn * 16 + m16];

    float* proj = reinterpret_cast<float*>(&Ab[0][0]);   // [128][68] f32, stride 68
#pragma unroll
    for (int tm = 0; tm < 2; tm++) {
#pragma unroll
        for (int r = 0; r < 4; r++) {
            const int eloc = wv * 32 + tm * 16 + quad * 4 + r;   // in [wv*32, wv*32+32)
            const float s = scale_s[eloc];
#pragma unroll
            for (int tn = 0; tn < 4; tn++) {
                float v = acc[tm][tn][r] + bias[tn];
                v = v > 0.f ? v : 0.f;
                proj[eloc * 68 + tn * 16 + m16] = v * s;
            }
        }
    }
    // NO barrier: wave wv wrote exactly proj rows [wv*32, wv*32+32) and reads
    // only those below. (src_s/scale_s were synced by the earlier barrier.)

    // wave-cooperative segmented reduce: lane = feature, walk 32 sorted edges,
    // flush one COALESCED 256B atomic burst per segment.
    {
        const int j0 = wv * 32;
        float sum = 0.f;
#pragma unroll
        for (int j = j0; j < j0 + 32; j++) {
            sum += proj[j * 68 + lane];
            const bool flush = (j == j0 + 31) || (src_s[j + 1] != src_s[j]);
            if (flush) {
                atomicAdd(out + (size_t)src_s[j] * 64 + lane, sum);
                sum = 0.f;
            }
        }
    }
}

extern "C" void kernel_launch(void* const* d_in, const int* in_sizes, int n_in,
                              void* d_out, int out_size, void* d_ws, size_t ws_size,
                              hipStream_t stream) {
    const float* x     = (const float*)d_in[0];
    const float* W     = (const float*)d_in[1];
    const float* b     = (const float*)d_in[2];
    const float* ea    = (const float*)d_in[3];
    const int*   edges = (const int*)d_in[4];
    float* out = (float*)d_out;

    char* ws = (char*)d_ws;
    unsigned short* xbf  = (unsigned short*)(ws + OFF_XBF);
    unsigned short* wT   = (unsigned short*)(ws + OFF_WT);
    unsigned* cnt_tot    = (unsigned*)(ws + OFF_CTOT);
    float* wgt           = (float*)(ws + OFF_WGT);
    unsigned* pe         = (unsigned*)(ws + OFF_PE);
    unsigned* pb         = (unsigned*)(ws + OFF_PB);
    int* sdst            = (int*)(ws + OFF_DST);
    int* seg             = (int*)(ws + OFF_SEG);

    // 1: out-zero, x->bf16, W^T, softmax + FUSED partition counts (raw pb)
    k_init<<<(NN * DD) / 256, 256, 0, stream>>>(x, W, ea, edges, xbf, wT, wgt, out, pb);

    // 2: partition scatter (self-scanning; k_pscan launch eliminated)
    k_pscat<<<dim3(PSPLIT, TT), 256, 0, stream>>>(edges, pb, pe);

    // 3: fused bucket sort (bcount+scan1+scan2+bfill collapsed into one)
    k_bsort<<<dim3(CH, TT), 512, 0, stream>>>(pe, pb, cnt_tot, sdst, seg);

    // 4: MFMA gather-GEMM + wave-cooperative segmented scatter (R0 proven)
    dim3 grid(EE / 128, TT);
    k_edge<<<grid, 256, 0, stream>>>(xbf, wT, b, sdst, seg, cnt_tot, wgt, out);
}